// Round 14
// baseline (98.772 us; speedup 1.0000x reference)
//
#include <hip/hip_runtime.h>
#include <math.h>

#define M_  2
#define B_  256
#define L_  1024
#define K_  4
#define S_  20
#define NR_ 100
#define NTERM 7   // Taylor terms T_1..T_7 ; ||mu*Q||inf <= 0.13 -> rem ~2e-11

typedef float f32x4_t __attribute__((ext_vector_type(4)));
typedef float f32x2_t __attribute__((ext_vector_type(2)));
typedef _Float16 f16;
typedef f16 f16x2 __attribute__((ext_vector_type(2)));
typedef f16 f16x4 __attribute__((ext_vector_type(4)));

__device__ __forceinline__ float softplusf(float x) {
    return x > 20.0f ? x : log1pf(expf(x));
}

__device__ __forceinline__ f16x2 asf16x2(float x) {
    union { float f; f16x2 h; } u; u.f = x; return u.h;
}

// ---------------------------------------------------------------------------
// Kernel 1: per (m,k): normalized Q, Taylor T_n = Q^n/n! (registers), then
// P[m,r,k] = I + sum_n mu_r^n T_n for ALL 100 r. 8 blocks, 512 threads.
// ---------------------------------------------------------------------------
__global__ __launch_bounds__(512)
void pmat_kernel(const float* __restrict__ tauk,   // (M,NR)
                 const float* __restrict__ exch,   // (M,K,S,S)
                 const float* __restrict__ equil,  // (M,K,S)
                 const float* __restrict__ pmrk,   // (M,K)
                 float*       __restrict__ Pws)    // (M,NR,K,400)
{
    __shared__ float sQ[400];
    __shared__ float sT[2][400];
    __shared__ float sRow[20];

    const int blk = blockIdx.x;          // mm*K_ + kk
    const int kk = blk % K_;
    const int mm = blk / K_;
    const int tid = threadIdx.x;
    const bool act = tid < 400;
    const int i = tid / 20;
    const int j = tid - i * 20;

    float p[20];
    float Q0 = 0.0f, rowsum = 0.0f;
    float tn[NTERM];

    if (act) {
        const float* eq = equil + (mm * K_ + kk) * S_;
        float mx = eq[0];
        #pragma unroll
        for (int z = 1; z < 20; ++z) mx = fmaxf(mx, eq[z]);
        float s = 0.0f;
        #pragma unroll
        for (int z = 0; z < 20; ++z) { p[z] = expf(eq[z] - mx); s += p[z]; }
        const float inv = 1.0f / s;
        #pragma unroll
        for (int z = 0; z < 20; ++z) p[z] *= inv;

        const float* Kx = exch + (mm * K_ + kk) * S_ * S_;
        float R = (i == j) ? 0.0f : softplusf(0.5f * (Kx[i * 20 + j] + Kx[j * 20 + i]));
        Q0 = R * p[j];
        sQ[tid] = Q0;
    }
    __syncthreads();

    if (act) {
        rowsum = 0.0f;
        #pragma unroll
        for (int z = 0; z < 20; ++z) rowsum += sQ[i * 20 + z];
        if (j == 0) sRow[i] = rowsum;
    }
    __syncthreads();

    if (act) {
        float mue = 0.0f;
        #pragma unroll
        for (int z = 0; z < 20; ++z) mue += p[z] * sRow[z];
        float q = (Q0 - ((i == j) ? rowsum : 0.0f)) / fmaxf(mue, 1e-16f);
        sQ[tid] = q;
        sT[0][tid] = q;
        tn[0] = q;                       // T_1 = Q
    }
    __syncthreads();

    int cur = 0;
    for (int n = 2; n <= NTERM; ++n) {
        if (act) {
            float acc = 0.0f;
            #pragma unroll
            for (int z = 0; z < 20; ++z) acc += sT[cur][i * 20 + z] * sQ[z * 20 + j];
            acc /= (float)n;
            tn[n - 1] = acc;             // T_n = Q^n / n!
            sT[cur ^ 1][tid] = acc;
        }
        __syncthreads();
        cur ^= 1;
    }

    if (act) {
        const float pm = softplusf(pmrk[mm * K_ + kk]);
        const float idn = (i == j) ? 1.0f : 0.0f;
        for (int rr = 0; rr < NR_; ++rr) {
            const float mu = softplusf(tauk[mm * NR_ + rr]) * pm;
            float a = idn;
            float mp = mu;
            #pragma unroll
            for (int n = 0; n < NTERM; ++n) { a = fmaf(mp, tn[n], a); mp *= mu; }
            Pws[((size_t)(mm * NR_ + rr) * K_ + kk) * 400 + tid] = a;
        }
    }
}

// ---------------------------------------------------------------------------
// Kernel 2: R10's proven structure (256 rows/block staged in LDS, one
// barrier, thread = (rg,t) computes 16 rows x 4 cols, NT full-row stores)
// with f16 data + v_dot2_f32_f16: 2 FMA/instr fp32-accumulate -> VALU
// halved (640 dot2 vs 1280 fma), LDS reads ~60 vs 100 b128, LDS 15.5 KB.
// Layouts: inH[row][z] f16 stride 48B (pairs over z); PpH[kcol][z2] f16x2
// stride 40B (kcol = k*20+s). 2048 blocks x 320 threads.
// ---------------------------------------------------------------------------
#define SPANR 256
#define TPB3  320

__device__ __forceinline__ void nt_store4(float* dst, const f32x4_t& v) {
    __builtin_nontemporal_store(v, (f32x4_t*)dst);
}

__global__ __launch_bounds__(TPB3)
void einsum_kernel(const float* __restrict__ inp,  // (M,B,L,S)
                   const float* __restrict__ Pws,  // (M,NR,K,400)
                   const int*   __restrict__ ridx, // (M,B)
                   float*       __restrict__ out)  // (M,B,L,K*S)
{
    __shared__ __align__(16) unsigned char inH[SPANR * 48];  // 12288 B
    __shared__ __align__(16) unsigned char PpH[80 * 40];     //  3200 B

    const int bx      = blockIdx.x;
    const int quarter = bx & 3;            // L_/SPANR = 4
    const int mb      = bx >> 2;           // 0..511
    const int mm      = mb >> 8;
    const int tid     = threadIdx.x;
    const int t       = tid % 20;
    const int rg      = tid / 20;          // 0..15
    const int k       = t / 5;
    const int c0      = (t % 5) * 4;

    const int r = ridx[mb];                // block-uniform
    const size_t row0 = (size_t)mb * L_ + (size_t)quarter * SPANR;

    // ---- stage input: 1280 float4 coalesced, f32->f16, rows stride 48B ----
    {
        const float4* Isrc = (const float4*)(inp + row0 * 20);
        #pragma unroll
        for (int q = 0; q < 4; ++q) {
            const int e  = tid + q * TPB3;     // 0..1279
            const int rr = e / 5;
            const int cc = e - rr * 5;
            const float4 v = Isrc[e];
            f16x4 h = { (f16)v.x, (f16)v.y, (f16)v.z, (f16)v.w };
            *(f16x4*)(inH + rr * 48 + cc * 8) = h;
        }
    }
    // ---- stage P pairs: PpH[kcol][z2] = (P[2z2][s], P[2z2+1][s]) ----
    {
        const float* Psrc = Pws + ((size_t)(mm * NR_ + r) * K_) * 400;
        #pragma unroll
        for (int q = 0; q < 5; ++q) {
            const int idx = tid + q * TPB3;    // 0..1599 = kk*400 + z*20 + s
            const int kk  = idx / 400;
            const int rem = idx - kk * 400;
            const int z   = rem / 20;
            const int s   = rem - z * 20;
            const float v = Psrc[idx];
            *(f16*)(PpH + (kk * 20 + s) * 40 + (z >> 1) * 4 + (z & 1) * 2) = (f16)v;
        }
    }
    __syncthreads();                       // the ONLY barrier

    // ---- P fragments into registers: 4 cols x 10 z2-pairs (24 VGPR) ----
    f32x4_t PA[4], PB[4];
    f32x2_t PC[4];
    #pragma unroll
    for (int i = 0; i < 4; ++i) {
        const unsigned char* pb = PpH + (k * 20 + c0 + i) * 40;
        PA[i] = *(const f32x4_t*)(pb);         // pairs z2 = 0..3
        PB[i] = *(const f32x4_t*)(pb + 16);    // pairs z2 = 4..7
        PC[i] = *(const f32x2_t*)(pb + 32);    // pairs z2 = 8..9
    }

    float* ob = out + row0 * 80 + k * 20 + c0;

    f32x4_t acc[16];
    #pragma unroll
    for (int rr = 0; rr < 16; ++rr) acc[rr] = (f32x4_t){0.f, 0.f, 0.f, 0.f};

    #pragma unroll
    for (int rr = 0; rr < 16; ++rr) {
        const int l = rg + rr * 16;
        const unsigned char* ib = inH + l * 48;
        const f32x4_t ia = *(const f32x4_t*)(ib);        // input pairs 0..3
        const f32x4_t iby = *(const f32x4_t*)(ib + 16);  // pairs 4..7
        const f32x2_t ic = *(const f32x2_t*)(ib + 32);   // pairs 8..9
        #pragma unroll
        for (int i = 0; i < 4; ++i) {
            float s = acc[rr][i];
            #pragma unroll
            for (int z2 = 0; z2 < 4; ++z2)
                s = __builtin_amdgcn_fdot2(asf16x2(ia[z2]), asf16x2(PA[i][z2]), s, false);
            #pragma unroll
            for (int z2 = 0; z2 < 4; ++z2)
                s = __builtin_amdgcn_fdot2(asf16x2(iby[z2]), asf16x2(PB[i][z2]), s, false);
            s = __builtin_amdgcn_fdot2(asf16x2(ic[0]), asf16x2(PC[i][0]), s, false);
            s = __builtin_amdgcn_fdot2(asf16x2(ic[1]), asf16x2(PC[i][1]), s, false);
            acc[rr][i] = s;
        }
    }

    #pragma unroll
    for (int rr = 0; rr < 16; ++rr) {
        const int l = rg + rr * 16;
        nt_store4(ob + (size_t)l * 80, acc[rr]);
    }
}

// ---------------------------------------------------------------------------
extern "C" void kernel_launch(void* const* d_in, const int* in_sizes, int n_in,
                              void* d_out, int out_size, void* d_ws, size_t ws_size,
                              hipStream_t stream) {
    const float* inp   = (const float*)d_in[0];  // (M,B,L,S)
    const float* tauk  = (const float*)d_in[1];  // (M,NR)
    const float* exch  = (const float*)d_in[2];  // (M,K,S,S)
    const float* equil = (const float*)d_in[3];  // (M,K,S)
    const float* pmrk  = (const float*)d_in[4];  // (M,K)
    const int*   ridx  = (const int*)d_in[5];    // (M,B)
    float* outp = (float*)d_out;

    float* Pws = (float*)d_ws;                   // M*NR*K*400*4 = 1.28 MB

    pmat_kernel<<<M_ * K_, 512, 0, stream>>>(tauk, exch, equil, pmrk, Pws);
    einsum_kernel<<<M_ * B_ * (L_ / SPANR), TPB3, 0, stream>>>(inp, Pws, ridx, outp);
}